// Round 12
// baseline (489.964 us; speedup 1.0000x reference)
//
#include <hip/hip_runtime.h>

// GAT (2-layer) on MI355X — partition-built CSR + LDS-tiled GEMM +
// 8-deep MLP edge passes; layer-2 GEMM fused into gather1's epilogue.
// Closed-form segment softmax: alpha in {+t,-t}; per-src s: p=#pos out-edges,
// deg=out-degree (incl self-loop).
//   w = (flag?1:c) * dinv[s],  dinv = p>0 ? 1/(p+(deg-p)c) : 1/(c*deg).
// After alpha: h[s] *= dinv[s] in place -> gather weight is (flag?1:c).
// edge_index arrives as int32 (harness converts integer inputs).
// R5: W reg-arrays spill -> W in LDS.  R6/R7/R8: __launch_bounds__(256,1)
// frees VGPRs; pad LDS tiles.  R8: naive hist = cross-XCD line ping-pong.
// R9: scattered 4B stores = 64B/line write amp -> partition build (R10).
// R10/R11: edge passes latency-bound; MLP-4 + dinv pre-scale -> 69us alpha.
// R11 counters: alpha FETCH = 8 x h (every XCD faults whole h) -> the floor
// is XCD replication; go deeper on MLP (8) and cut the gemm16 round-trip.
#define EXPC 0.13533528323661270f  // exp(-2*1.0)
#define REP 8
#define CHUNK 16384  // edges per partition block

__global__ void zero_i32(int* __restrict__ p, int n) {
  int i = blockIdx.x * blockDim.x + threadIdx.x;
  if (i < n) p[i] = 0;
}

// ---------------- layer-1 GEMM (unchanged from R8) ----------------
template <bool RELU_IN>
__global__ void __launch_bounds__(256, 1)
gemm64_k(const float* __restrict__ x, const float* __restrict__ W,
         float* __restrict__ h, int N) {
  __shared__ float xs[64][68];
  __shared__ float wt[64][68];  // wt[k][c] = W[c][k]
  const int t = threadIdx.x;
  const int r0 = blockIdx.x * 64;
  for (int i = t; i < 4096; i += 256) {
    int c = i >> 6, k = i & 63;
    wt[k][c] = W[i];
  }
  for (int s = t; s < 1024; s += 256) {
    int r = s >> 4, c4 = (s & 15) << 2;
    float4 v = make_float4(0.f, 0.f, 0.f, 0.f);
    if (r0 + r < N) {
      v = *(const float4*)(x + (size_t)(r0 + r) * 64 + c4);
      if (RELU_IN) {
        v.x = fmaxf(v.x, 0.f); v.y = fmaxf(v.y, 0.f);
        v.z = fmaxf(v.z, 0.f); v.w = fmaxf(v.w, 0.f);
      }
    }
    *(float4*)(&xs[r][c4]) = v;
  }
  __syncthreads();
  const int ty = t >> 4, tx = t & 15;
  float acc[4][4] = {};
  for (int kk = 0; kk < 64; kk += 4) {
    float4 a[4], w[4];
#pragma unroll
    for (int i = 0; i < 4; i++) a[i] = *(const float4*)(&xs[4 * ty + i][kk]);
#pragma unroll
    for (int m = 0; m < 4; m++) w[m] = *(const float4*)(&wt[kk + m][4 * tx]);
#pragma unroll
    for (int i = 0; i < 4; i++) {
      acc[i][0] = fmaf(a[i].x, w[0].x, fmaf(a[i].y, w[1].x,
                  fmaf(a[i].z, w[2].x, fmaf(a[i].w, w[3].x, acc[i][0]))));
      acc[i][1] = fmaf(a[i].x, w[0].y, fmaf(a[i].y, w[1].y,
                  fmaf(a[i].z, w[2].y, fmaf(a[i].w, w[3].y, acc[i][1]))));
      acc[i][2] = fmaf(a[i].x, w[0].z, fmaf(a[i].y, w[1].z,
                  fmaf(a[i].z, w[2].z, fmaf(a[i].w, w[3].z, acc[i][2]))));
      acc[i][3] = fmaf(a[i].x, w[0].w, fmaf(a[i].y, w[1].w,
                  fmaf(a[i].z, w[2].w, fmaf(a[i].w, w[3].w, acc[i][3]))));
    }
  }
#pragma unroll
  for (int i = 0; i < 4; i++) {
    int row = r0 + 4 * ty + i;
    if (row < N)
      *(float4*)(h + (size_t)row * 64 + 4 * tx) =
          make_float4(acc[i][0], acc[i][1], acc[i][2], acc[i][3]);
  }
}

// ---------------- partition-based CSR build (unchanged from R10) ----------------
__global__ void passA_k(const int* __restrict__ ei, int* __restrict__ chd,
                        int* __restrict__ chs, int E, int Et) {
  __shared__ int ld[512], ls[512];
  int t = threadIdx.x;
  for (int i = t; i < 512; i += 256) { ld[i] = 0; ls[i] = 0; }
  __syncthreads();
  int base = blockIdx.x * CHUNK;
  int end = base + CHUNK; if (end > Et) end = Et;
  for (int e = base + t; e < end; e += 256) {
    int s, d;
    if (e < E) { s = ei[e]; d = ei[E + e]; } else { s = e - E; d = s; }
    atomicAdd(&ld[d >> 8], 1);
    atomicAdd(&ls[s >> 8], 1);
  }
  __syncthreads();
  for (int i = t; i < 512; i += 256) {
    if (ld[i]) atomicAdd(chd + i, ld[i]);
    if (ls[i]) atomicAdd(chs + i, ls[i]);
  }
}

__global__ void scan2_k(const int* __restrict__ chd, const int* __restrict__ chs,
                        int* __restrict__ cbd, int* __restrict__ cbs,
                        int* __restrict__ cud, int* __restrict__ cus, int NB) {
  __shared__ int l[512];
  int t = threadIdx.x;
  for (int pass = 0; pass < 2; ++pass) {
    const int* src = pass ? chs : chd;
    int* db = pass ? cbs : cbd;
    int* dc = pass ? cus : cud;
    int v = (t < NB) ? src[t] : 0;
    l[t] = v;
    __syncthreads();
    for (int o = 1; o < 512; o <<= 1) {
      int a = (t >= o) ? l[t - o] : 0;
      __syncthreads();
      l[t] += a;
      __syncthreads();
    }
    if (t < NB) { int e = l[t] - v; db[t] = e; dc[t] = e; }
    __syncthreads();
  }
}

__global__ void passB_k(const int* __restrict__ ei, int* __restrict__ cud,
                        int* __restrict__ cus, int* __restrict__ part_dst,
                        unsigned char* __restrict__ part_src, int E, int Et) {
  __shared__ int cntd[512], cnts[512], based[512], bases[512];
  int t = threadIdx.x;
  for (int i = t; i < 512; i += 256) { cntd[i] = 0; cnts[i] = 0; }
  __syncthreads();
  int base = blockIdx.x * CHUNK;
  int end = base + CHUNK; if (end > Et) end = Et;
  for (int e = base + t; e < end; e += 256) {
    int s, d;
    if (e < E) { s = ei[e]; d = ei[E + e]; } else { s = e - E; d = s; }
    atomicAdd(&cntd[d >> 8], 1);
    atomicAdd(&cnts[s >> 8], 1);
  }
  __syncthreads();
  for (int i = t; i < 512; i += 256) {
    based[i] = cntd[i] ? atomicAdd(cud + i, cntd[i]) : 0;
    bases[i] = cnts[i] ? atomicAdd(cus + i, cnts[i]) : 0;
    cntd[i] = 0; cnts[i] = 0;
  }
  __syncthreads();
  for (int e = base + t; e < end; e += 256) {
    int s, d;
    if (e < E) { s = ei[e]; d = ei[E + e]; } else { s = e - E; d = s; }
    int bd = d >> 8, bs = s >> 8;
    int rd = atomicAdd(&cntd[bd], 1);
    int rs = atomicAdd(&cnts[bs], 1);
    part_dst[based[bd] + rd] = s | ((d & 255) << 17);
    part_src[bases[bs] + rs] = (unsigned char)(s & 255);
  }
}

__global__ void passC_k(const int* __restrict__ part_dst, const int* __restrict__ cbd,
                        const int* __restrict__ chd, int* __restrict__ csr_src,
                        int* __restrict__ in_deg, int* __restrict__ off, int N) {
  __shared__ int hist[256], loff[256], rank[256];
  int b = blockIdx.x, t = threadIdx.x;
  int segbase = cbd[b], segcnt = chd[b];
  hist[t] = 0; rank[t] = 0;
  __syncthreads();
  for (int i = t; i < segcnt; i += 256)
    atomicAdd(&hist[part_dst[segbase + i] >> 17], 1);
  __syncthreads();
  int x = hist[t];
  loff[t] = x;
  __syncthreads();
  for (int o = 1; o < 256; o <<= 1) {
    int a = (t >= o) ? loff[t - o] : 0;
    __syncthreads();
    loff[t] += a;
    __syncthreads();
  }
  int excl = loff[t] - x;
  int node = (b << 8) + t;
  if (node < N) { in_deg[node] = x; off[node] = segbase + excl; }
  __syncthreads();
  loff[t] = excl;
  __syncthreads();
  for (int i = t; i < segcnt; i += 256) {
    int rec = part_dst[segbase + i];
    int dl = rec >> 17;
    int r = atomicAdd(&rank[dl], 1);
    csr_src[segbase + loff[dl] + r] = rec & 0x1FFFF;
  }
}

__global__ void passCs_k(const unsigned char* __restrict__ part_src,
                         const int* __restrict__ cbs, const int* __restrict__ chs,
                         int* __restrict__ deg, int N) {
  __shared__ int hist[256];
  int b = blockIdx.x, t = threadIdx.x;
  int segbase = cbs[b], segcnt = chs[b];
  hist[t] = 0;
  __syncthreads();
  for (int i = t; i < segcnt; i += 256)
    atomicAdd(&hist[part_src[segbase + i]], 1);
  __syncthreads();
  int node = (b << 8) + t;
  if (node < N) deg[node] = hist[t];
}

// ---------------- per-layer edge passes (8-deep MLP) ----------------
template <int D>
__global__ void __launch_bounds__(256, 1)
alpha_csr_k(const int* __restrict__ csr_src, const int* __restrict__ off,
            const int* __restrict__ indeg, const float* __restrict__ h,
            unsigned char* __restrict__ flagb, int* __restrict__ pos_rep, int N) {
  const int G = D / 4;
  int t = blockIdx.x * 256 + threadIdx.x;
  int node = t / G;
  int c = t & (G - 1);
  if (node >= N) return;
  int* pos = pos_rep + (blockIdx.x & (REP - 1)) * N;
  const float4 hd = *(const float4*)(h + (size_t)node * D + c * 4);
  int j = off[node];
  int je = j + indeg[node];
  for (; j + 8 <= je; j += 8) {
    int s[8];
    float4 a[8];
#pragma unroll
    for (int u = 0; u < 8; u++) s[u] = csr_src[j + u];
#pragma unroll
    for (int u = 0; u < 8; u++) a[u] = *(const float4*)(h + (size_t)s[u] * D + c * 4);
    float p[8];
#pragma unroll
    for (int u = 0; u < 8; u++)
      p[u] = fmaf(a[u].x, hd.x, fmaf(a[u].y, hd.y, fmaf(a[u].z, hd.z, a[u].w * hd.w)));
#pragma unroll
    for (int o = G / 2; o > 0; o >>= 1) {
#pragma unroll
      for (int u = 0; u < 8; u++) p[u] += __shfl_xor(p[u], o);
    }
    if (c == 0) {
#pragma unroll
      for (int u = 0; u < 8; u++) {
        bool z = p[u] > 0.f;
        flagb[j + u] = (unsigned char)z;
        if (z) atomicAdd(pos + s[u], 1);
      }
    }
  }
  for (; j < je; ++j) {
    int s = csr_src[j];
    float4 hs = *(const float4*)(h + (size_t)s * D + c * 4);
    float p = fmaf(hs.x, hd.x, fmaf(hs.y, hd.y, fmaf(hs.z, hd.z, hs.w * hd.w)));
#pragma unroll
    for (int o = G / 2; o > 0; o >>= 1) p += __shfl_xor(p, o);
    if (c == 0) {
      bool pz = p > 0.f;
      flagb[j] = (unsigned char)pz;
      if (pz) atomicAdd(pos + s, 1);
    }
  }
}

// Fused denom + in-place scale.
template <int D>
__global__ void denom_scale_k(const int* __restrict__ pos_rep, const int* __restrict__ deg,
                              float* __restrict__ h, int N) {
  const int G = D / 4;
  int t = blockIdx.x * 256 + threadIdx.x;
  int node = t / G;
  int c = t & (G - 1);
  if (node >= N) return;
  float dinv = 0.f;
  if (c == 0) {
    int p = 0;
#pragma unroll
    for (int r = 0; r < REP; r++) p += pos_rep[r * N + node];
    int dg = deg[node];
    dinv = (p > 0) ? 1.f / ((float)p + (float)(dg - p) * EXPC)
                   : 1.f / (EXPC * (float)dg);
  }
  dinv = __shfl(dinv, 0, G);
  float4* hp = (float4*)(h + (size_t)node * D + c * 4);
  float4 v = *hp;
  v.x *= dinv; v.y *= dinv; v.z *= dinv; v.w *= dinv;
  *hp = v;
}

// Layer-1 gather with fused relu + 64->16 GEMM epilogue. 16 lanes per node.
// Epilogue: lane c computes out channel c: shfl-broadcast row chunks,
// W2^T staged in wt2[16][68] (row base 272B = 16B-aligned; 2-way banks).
__global__ void __launch_bounds__(256, 1)
gather1_g16_k(const int* __restrict__ csr_src, const int* __restrict__ off,
              const int* __restrict__ indeg, const unsigned char* __restrict__ flagb,
              const float* __restrict__ h, const float* __restrict__ b1,
              const float* __restrict__ W2, float* __restrict__ h2, int N) {
  __shared__ float wt2[16][68];  // wt2[j][k] = W2[j*64+k]
  const int t = threadIdx.x;
  for (int i = t; i < 1024; i += 256) wt2[i >> 6][i & 63] = W2[i];
  __syncthreads();
  int g = blockIdx.x * 256 + t;
  int node = g >> 4;
  int c = g & 15;
  if (node >= N) return;
  float4 acc = *(const float4*)(b1 + c * 4);
  int j = off[node];
  int je = j + indeg[node];
  for (; j + 8 <= je; j += 8) {
    int s[8];
    float w[8];
    float4 v[8];
#pragma unroll
    for (int u = 0; u < 8; u++) s[u] = csr_src[j + u];
#pragma unroll
    for (int u = 0; u < 8; u++) w[u] = flagb[j + u] ? 1.f : EXPC;
#pragma unroll
    for (int u = 0; u < 8; u++) v[u] = *(const float4*)(h + (size_t)s[u] * 64 + c * 4);
#pragma unroll
    for (int u = 0; u < 8; u++) {
      acc.x = fmaf(w[u], v[u].x, acc.x);
      acc.y = fmaf(w[u], v[u].y, acc.y);
      acc.z = fmaf(w[u], v[u].z, acc.z);
      acc.w = fmaf(w[u], v[u].w, acc.w);
    }
  }
  for (; j < je; ++j) {
    int s = csr_src[j];
    float w = flagb[j] ? 1.f : EXPC;
    float4 hv = *(const float4*)(h + (size_t)s * 64 + c * 4);
    acc.x = fmaf(w, hv.x, acc.x);
    acc.y = fmaf(w, hv.y, acc.y);
    acc.z = fmaf(w, hv.z, acc.z);
    acc.w = fmaf(w, hv.w, acc.w);
  }
  // relu
  acc.x = fmaxf(acc.x, 0.f); acc.y = fmaxf(acc.y, 0.f);
  acc.z = fmaxf(acc.z, 0.f); acc.w = fmaxf(acc.w, 0.f);
  // 64->16 GEMM: lane c computes channel c over the node's 64-row.
  int lanebase = (threadIdx.x & 63) & 48;  // group base within wave
  float o = 0.f;
#pragma unroll
  for (int s16 = 0; s16 < 16; s16++) {
    int src = lanebase + s16;
    float cx = __shfl(acc.x, src);
    float cy = __shfl(acc.y, src);
    float cz = __shfl(acc.z, src);
    float cw = __shfl(acc.w, src);
    float4 wv = *(const float4*)(&wt2[c][4 * s16]);
    o = fmaf(cx, wv.x, fmaf(cy, wv.y, fmaf(cz, wv.z, fmaf(cw, wv.w, o))));
  }
  h2[(size_t)node * 16 + c] = o;
}

// Layer-2 gather (D=16, h pre-scaled), fused log-softmax. 8-deep MLP.
__global__ void __launch_bounds__(256, 1)
gather2_k(const int* __restrict__ csr_src, const int* __restrict__ off,
          const int* __restrict__ indeg, const unsigned char* __restrict__ flagb,
          const float* __restrict__ h, const float* __restrict__ b2,
          float* __restrict__ outp, int N) {
  int t = blockIdx.x * 256 + threadIdx.x;
  int node = t >> 2;
  int c = t & 3;
  if (node >= N) return;
  float4 acc = *(const float4*)(b2 + c * 4);
  int j = off[node];
  int je = j + indeg[node];
  for (; j + 8 <= je; j += 8) {
    int s[8];
    float w[8];
    float4 v[8];
#pragma unroll
    for (int u = 0; u < 8; u++) s[u] = csr_src[j + u];
#pragma unroll
    for (int u = 0; u < 8; u++) w[u] = flagb[j + u] ? 1.f : EXPC;
#pragma unroll
    for (int u = 0; u < 8; u++) v[u] = *(const float4*)(h + (size_t)s[u] * 16 + c * 4);
#pragma unroll
    for (int u = 0; u < 8; u++) {
      acc.x = fmaf(w[u], v[u].x, acc.x);
      acc.y = fmaf(w[u], v[u].y, acc.y);
      acc.z = fmaf(w[u], v[u].z, acc.z);
      acc.w = fmaf(w[u], v[u].w, acc.w);
    }
  }
  for (; j < je; ++j) {
    int s = csr_src[j];
    float w = flagb[j] ? 1.f : EXPC;
    float4 hv = *(const float4*)(h + (size_t)s * 16 + c * 4);
    acc.x = fmaf(w, hv.x, acc.x);
    acc.y = fmaf(w, hv.y, acc.y);
    acc.z = fmaf(w, hv.z, acc.z);
    acc.w = fmaf(w, hv.w, acc.w);
  }
  float m = fmaxf(fmaxf(acc.x, acc.y), fmaxf(acc.z, acc.w));
  m = fmaxf(m, __shfl_xor(m, 1));
  m = fmaxf(m, __shfl_xor(m, 2));
  float s = expf(acc.x - m) + expf(acc.y - m) + expf(acc.z - m) + expf(acc.w - m);
  s += __shfl_xor(s, 1);
  s += __shfl_xor(s, 2);
  float lse = m + logf(s);
  acc.x -= lse; acc.y -= lse; acc.z -= lse; acc.w -= lse;
  *(float4*)(outp + (size_t)node * 16 + c * 4) = acc;
}

extern "C" void kernel_launch(void* const* d_in, const int* in_sizes, int n_in,
                              void* d_out, int out_size, void* d_ws, size_t ws_size,
                              hipStream_t stream) {
  const float* x = (const float*)d_in[0];
  const int* ei = (const int*)d_in[1];
  const float* W1 = (const float*)d_in[2];
  const float* b1 = (const float*)d_in[3];
  const float* W2 = (const float*)d_in[4];
  const float* b2 = (const float*)d_in[5];
  float* out = (float*)d_out;

  const int N = in_sizes[0] / 64;
  const int E = in_sizes[1] / 2;
  const int Et = E + N;
  const int B = 256;
  const int nbT = (N + 63) / 64;             // GEMM tiles
  const int NB = (N + 255) >> 8;             // coarse buckets (<=512)
  const int nbP = (Et + CHUNK - 1) / CHUNK;  // partition chunks

  // Workspace (~49 MB). Partition arrays dead after pass C/C' -> pos_rep/flagb alias.
  char* ws = (char*)d_ws;
  float* h1 = (float*)ws;    ws += (size_t)N * 64 * 4;   // 25.6 MB
  float* h2 = (float*)ws;    ws += (size_t)N * 16 * 4;   // 6.4 MB
  int* deg = (int*)ws;       ws += (size_t)N * 4;
  int* in_deg = (int*)ws;    ws += (size_t)N * 4;
  int* off = (int*)ws;       ws += (size_t)N * 4;
  int* chd = (int*)ws;       ws += 512 * 4;
  int* chs = (int*)ws;       ws += 512 * 4;
  int* cbd = (int*)ws;       ws += 512 * 4;
  int* cbs = (int*)ws;       ws += 512 * 4;
  int* cud = (int*)ws;       ws += 512 * 4;
  int* cus = (int*)ws;       ws += 512 * 4;
  int* csr_src = (int*)ws;   ws += (size_t)Et * 4;       // 6.8 MB
  char* P = ws;              ws += (size_t)Et * 4 + (size_t)Et;  // 8.5 MB
  int* part_dst = (int*)P;
  unsigned char* part_src = (unsigned char*)(P + (size_t)Et * 4);
  int* pos_rep = (int*)P;                        // alias (after pass C/C')
  unsigned char* flagb = (unsigned char*)(P + (size_t)REP * N * 4);

  // ---- CSR structure (partition pipeline, data-independent) ----
  hipLaunchKernelGGL(zero_i32, dim3(4), dim3(B), 0, stream, chd, 1024);  // chd+chs
  hipLaunchKernelGGL(passA_k, dim3(nbP), dim3(B), 0, stream, ei, chd, chs, E, Et);
  hipLaunchKernelGGL(scan2_k, dim3(1), dim3(512), 0, stream, chd, chs, cbd, cbs, cud, cus, NB);
  hipLaunchKernelGGL(passB_k, dim3(nbP), dim3(B), 0, stream, ei, cud, cus,
                     part_dst, part_src, E, Et);
  hipLaunchKernelGGL(passC_k, dim3(NB), dim3(B), 0, stream, part_dst, cbd, chd,
                     csr_src, in_deg, off, N);
  hipLaunchKernelGGL(passCs_k, dim3(NB), dim3(B), 0, stream, part_src, cbs, chs, deg, N);

  // ---- layer 1 (D=64) ----
  hipLaunchKernelGGL((gemm64_k<false>), dim3(nbT), dim3(B), 0, stream, x, W1, h1, N);
  hipLaunchKernelGGL(zero_i32, dim3((REP * N + B - 1) / B), dim3(B), 0, stream,
                     pos_rep, REP * N);
  hipLaunchKernelGGL((alpha_csr_k<64>), dim3(((size_t)N * 16 + B - 1) / B), dim3(B), 0,
                     stream, csr_src, off, in_deg, h1, flagb, pos_rep, N);
  hipLaunchKernelGGL((denom_scale_k<64>), dim3(((size_t)N * 16 + B - 1) / B), dim3(B), 0,
                     stream, pos_rep, deg, h1, N);
  hipLaunchKernelGGL(gather1_g16_k, dim3(((size_t)N * 16 + B - 1) / B), dim3(B), 0,
                     stream, csr_src, off, in_deg, flagb, h1, b1, W2, h2, N);

  // ---- layer 2 (D=16): log-softmax fused into gather ----
  hipLaunchKernelGGL(zero_i32, dim3((REP * N + B - 1) / B), dim3(B), 0, stream,
                     pos_rep, REP * N);
  hipLaunchKernelGGL((alpha_csr_k<16>), dim3(((size_t)N * 4 + B - 1) / B), dim3(B), 0,
                     stream, csr_src, off, in_deg, h2, flagb, pos_rep, N);
  hipLaunchKernelGGL((denom_scale_k<16>), dim3(((size_t)N * 4 + B - 1) / B), dim3(B), 0,
                     stream, pos_rep, deg, h2, N);
  hipLaunchKernelGGL(gather2_k, dim3(((size_t)N * 4 + B - 1) / B), dim3(B), 0,
                     stream, csr_src, off, in_deg, flagb, h2, b2, out, N);
}